// Round 1
// baseline (3380.098 us; speedup 1.0000x reference)
//
#include <hip/hip_runtime.h>
#include <math.h>

#define N_NODES 100000
#define N_EDGES 1200000
#define DIM 64

// ---------------- degree / dinv ----------------

__global__ void k_count(const int* __restrict__ dst, int* __restrict__ cnt) {
    int e = blockIdx.x * blockDim.x + threadIdx.x;
    if (e < N_EDGES) atomicAdd(&cnt[dst[e]], 1);
}

__global__ void k_dinv(float* __restrict__ dinv_buf) {
    int i = blockIdx.x * blockDim.x + threadIdx.x;
    if (i < N_NODES) {
        int c = ((const int*)dinv_buf)[i];          // in-place: int count -> float dinv
        dinv_buf[i] = rsqrtf((float)(c + 1));       // +1 self-loop; always >= 1
    }
}

// ---------------- dense h = relu?(x) @ W ----------------
// block = 256 (4 waves); each wave handles 8 nodes, lane = output column j.
// 3125 blocks * 32 nodes = 100000 exactly.

template <bool RELU_IN>
__global__ void k_gemm(const float* __restrict__ x, const float* __restrict__ W,
                       float* __restrict__ h) {
    __shared__ float Wlds[DIM * DIM];
    int tid = threadIdx.x;
    for (int i = tid * 4; i < DIM * DIM; i += 256 * 4)
        *(float4*)&Wlds[i] = *(const float4*)&W[i];
    __syncthreads();

    int wave = tid >> 6;
    int lane = tid & 63;
    int n0 = (blockIdx.x * 4 + wave) * 8;
    if (n0 >= N_NODES) return;

    float acc[8];
#pragma unroll
    for (int m = 0; m < 8; ++m) acc[m] = 0.f;

    for (int k4 = 0; k4 < DIM / 4; ++k4) {
        float4 xv[8];
#pragma unroll
        for (int m = 0; m < 8; ++m) {
            xv[m] = *(const float4*)&x[(size_t)(n0 + m) * DIM + k4 * 4];
            if (RELU_IN) {
                xv[m].x = fmaxf(xv[m].x, 0.f);
                xv[m].y = fmaxf(xv[m].y, 0.f);
                xv[m].z = fmaxf(xv[m].z, 0.f);
                xv[m].w = fmaxf(xv[m].w, 0.f);
            }
        }
#pragma unroll
        for (int kk = 0; kk < 4; ++kk) {
            float wk = Wlds[(k4 * 4 + kk) * DIM + lane];
#pragma unroll
            for (int m = 0; m < 8; ++m) {
                float xs = (kk == 0) ? xv[m].x : (kk == 1) ? xv[m].y
                         : (kk == 2) ? xv[m].z : xv[m].w;
                acc[m] = fmaf(xs, wk, acc[m]);
            }
        }
    }
#pragma unroll
    for (int m = 0; m < 8; ++m)
        h[(size_t)(n0 + m) * DIM + lane] = acc[m];
}

// ---------------- self-loop + bias init (full overwrite of out) ----------------
// thread per (node, float4-quad): N_NODES*16 threads.

__global__ void k_self(const float* __restrict__ h, const float* __restrict__ dinv,
                       const float* __restrict__ b, float* __restrict__ out) {
    int idx = blockIdx.x * blockDim.x + threadIdx.x;
    if (idx >= N_NODES * 16) return;
    int n = idx >> 4, q = idx & 15;
    float s = dinv[n];
    s = s * s;
    float4 hv = *(const float4*)&h[(size_t)n * DIM + q * 4];
    float4 bv = *(const float4*)&b[q * 4];
    float4 o;
    o.x = fmaf(hv.x, s, bv.x);
    o.y = fmaf(hv.y, s, bv.y);
    o.z = fmaf(hv.z, s, bv.z);
    o.w = fmaf(hv.w, s, bv.w);
    *(float4*)&out[(size_t)n * DIM + q * 4] = o;
}

// ---------------- edge scatter: out[dst] += h[src] * dinv[src]*dinv[dst] ----------------
// thread per (edge, quad): 16 threads/edge -> coalesced 256B row gather, 4 atomics each.

__global__ void k_scatter(const float* __restrict__ h, const float* __restrict__ dinv,
                          const int* __restrict__ src, const int* __restrict__ dst,
                          float* __restrict__ out) {
    long long gid = (long long)blockIdx.x * blockDim.x + threadIdx.x;
    int e = (int)(gid >> 4);
    if (e >= N_EDGES) return;
    int q = (int)(gid & 15);
    int s = src[e], d = dst[e];
    float nrm = dinv[s] * dinv[d];
    float4 hv = *(const float4*)&h[(size_t)s * DIM + q * 4];
    float* o = &out[(size_t)d * DIM + q * 4];
    atomicAdd(o + 0, hv.x * nrm);
    atomicAdd(o + 1, hv.y * nrm);
    atomicAdd(o + 2, hv.z * nrm);
    atomicAdd(o + 3, hv.w * nrm);
}

// ---------------- launch ----------------

extern "C" void kernel_launch(void* const* d_in, const int* in_sizes, int n_in,
                              void* d_out, int out_size, void* d_ws, size_t ws_size,
                              hipStream_t stream) {
    const float* x   = (const float*)d_in[0];
    const int*   ei  = (const int*)d_in[1];     // [2, E] row-major
    const float* W1  = (const float*)d_in[2];
    const float* b1  = (const float*)d_in[3];
    const float* W2  = (const float*)d_in[4];
    const float* b2  = (const float*)d_in[5];
    const float* W3  = (const float*)d_in[6];
    const float* b3  = (const float*)d_in[7];
    float* out = (float*)d_out;

    const int* src = ei;
    const int* dst = ei + N_EDGES;

    char* ws = (char*)d_ws;
    float* dinv = (float*)ws;                         // 400 KB (int counts, then float)
    float* bufA = (float*)(ws + (1u << 20));          // 25.6 MB
    float* bufB = (float*)(ws + (1u << 20) + 26648576u); // 25.6 MB (256B-aligned offset)

    // degree -> dinv
    hipMemsetAsync(dinv, 0, N_NODES * sizeof(int), stream);
    k_count<<<(N_EDGES + 255) / 256, 256, 0, stream>>>(dst, (int*)dinv);
    k_dinv<<<(N_NODES + 255) / 256, 256, 0, stream>>>(dinv);

    const int gemm_blocks    = (N_NODES + 31) / 32;        // 3125
    const int self_blocks    = (N_NODES * 16 + 255) / 256; // 6250
    const int scatter_blocks = (int)(((long long)N_EDGES * 16 + 255) / 256); // 75000

    // Layer 1: x -> bufA (h), aggregate -> bufB
    k_gemm<false><<<gemm_blocks, 256, 0, stream>>>(x, W1, bufA);
    k_self<<<self_blocks, 256, 0, stream>>>(bufA, dinv, b1, bufB);
    k_scatter<<<scatter_blocks, 256, 0, stream>>>(bufA, dinv, src, dst, bufB);

    // Layer 2: relu(bufB) -> bufA (h), aggregate -> bufB (bufB consumed by gemm first)
    k_gemm<true><<<gemm_blocks, 256, 0, stream>>>(bufB, W2, bufA);
    k_self<<<self_blocks, 256, 0, stream>>>(bufA, dinv, b2, bufB);
    k_scatter<<<scatter_blocks, 256, 0, stream>>>(bufA, dinv, src, dst, bufB);

    // Layer 3: relu(bufB) -> bufA (h), aggregate -> d_out
    k_gemm<true><<<gemm_blocks, 256, 0, stream>>>(bufB, W3, bufA);
    k_self<<<self_blocks, 256, 0, stream>>>(bufA, dinv, b3, out);
    k_scatter<<<scatter_blocks, 256, 0, stream>>>(bufA, dinv, src, dst, out);
}

// Round 2
// 903.834 us; speedup vs baseline: 3.7397x; 3.7397x over previous
//
#include <hip/hip_runtime.h>
#include <math.h>

#define N_NODES 100000
#define N_EDGES 1200000
#define DIM 64

// ---------------- degree histogram ----------------

__global__ void k_count(const int* __restrict__ dst, int* __restrict__ cnt) {
    int e = blockIdx.x * blockDim.x + threadIdx.x;
    if (e < N_EDGES) atomicAdd(&cnt[dst[e]], 1);
}

__global__ void k_dinv(const int* __restrict__ cnt, float* __restrict__ dinv) {
    int i = blockIdx.x * blockDim.x + threadIdx.x;
    if (i < N_NODES) dinv[i] = rsqrtf((float)(cnt[i] + 1));  // +1 self-loop
}

// ---------------- single-block exclusive scan (100k ints) ----------------

__global__ void k_scan(const int* __restrict__ cnt, int* __restrict__ off,
                       int* __restrict__ cur) {
    __shared__ int buf[1024];
    __shared__ int carry;
    int tid = threadIdx.x;
    if (tid == 0) carry = 0;
    __syncthreads();
    for (int base = 0; base < N_NODES; base += 1024) {
        int i = base + tid;
        int v = (i < N_NODES) ? cnt[i] : 0;
        buf[tid] = v;
        __syncthreads();
        for (int ofs = 1; ofs < 1024; ofs <<= 1) {       // Hillis-Steele inclusive
            int t = (tid >= ofs) ? buf[tid - ofs] : 0;
            __syncthreads();
            buf[tid] += t;
            __syncthreads();
        }
        int incl = buf[tid];
        int excl = carry + incl - v;
        if (i < N_NODES) { off[i] = excl; cur[i] = excl; }
        __syncthreads();
        if (tid == 1023) carry += incl;                   // buf[1023] = chunk total
        __syncthreads();
    }
}

// ---------------- CSR bucket fill (one-time int atomics) ----------------

__global__ void k_fill(const int* __restrict__ src, const int* __restrict__ dst,
                       int* __restrict__ cur, int* __restrict__ csr_src) {
    int e = blockIdx.x * blockDim.x + threadIdx.x;
    if (e < N_EDGES) {
        int pos = atomicAdd(&cur[dst[e]], 1);
        csr_src[pos] = src[e];
    }
}

// ---------------- dense h = x @ W ----------------
// block = 256 (4 waves); each wave handles 8 nodes, lane = output column j.

__global__ void k_gemm(const float* __restrict__ x, const float* __restrict__ W,
                       float* __restrict__ h) {
    __shared__ float Wlds[DIM * DIM];
    int tid = threadIdx.x;
    for (int i = tid * 4; i < DIM * DIM; i += 256 * 4)
        *(float4*)&Wlds[i] = *(const float4*)&W[i];
    __syncthreads();

    int wave = tid >> 6;
    int lane = tid & 63;
    int n0 = (blockIdx.x * 4 + wave) * 8;
    if (n0 >= N_NODES) return;

    float acc[8];
#pragma unroll
    for (int m = 0; m < 8; ++m) acc[m] = 0.f;

    for (int k4 = 0; k4 < DIM / 4; ++k4) {
        float4 xv[8];
#pragma unroll
        for (int m = 0; m < 8; ++m)
            xv[m] = *(const float4*)&x[(size_t)(n0 + m) * DIM + k4 * 4];
#pragma unroll
        for (int kk = 0; kk < 4; ++kk) {
            float wk = Wlds[(k4 * 4 + kk) * DIM + lane];
#pragma unroll
            for (int m = 0; m < 8; ++m) {
                float xs = (kk == 0) ? xv[m].x : (kk == 1) ? xv[m].y
                         : (kk == 2) ? xv[m].z : xv[m].w;
                acc[m] = fmaf(xs, wk, acc[m]);
            }
        }
    }
#pragma unroll
    for (int m = 0; m < 8; ++m)
        h[(size_t)(n0 + m) * DIM + lane] = acc[m];
}

// ---------------- gather-side aggregation, fused self-loop + bias (+ relu) ----
// One wave per destination node; lane = output column. No atomics.

template <bool RELU_OUT>
__global__ void k_gather(const float* __restrict__ h, const float* __restrict__ dinv,
                         const int* __restrict__ off, const int* __restrict__ cnt,
                         const int* __restrict__ csr_src, const float* __restrict__ b,
                         float* __restrict__ out) {
    int node = blockIdx.x * (blockDim.x >> 6) + (threadIdx.x >> 6);
    int lane = threadIdx.x & 63;
    if (node >= N_NODES) return;

    float dd = dinv[node];
    float acc = fmaf(h[(size_t)node * DIM + lane], dd * dd, b[lane]);  // self-loop + bias

    int s0 = off[node];
    int n  = cnt[node];
    for (int i = 0; i < n; ++i) {
        int s = csr_src[s0 + i];                      // wave-uniform broadcast load
        float nrm = dinv[s] * dd;
        acc = fmaf(h[(size_t)s * DIM + lane], nrm, acc);  // coalesced 256B row gather
    }
    if (RELU_OUT) acc = fmaxf(acc, 0.f);
    out[(size_t)node * DIM + lane] = acc;
}

// ---------------- launch ----------------

extern "C" void kernel_launch(void* const* d_in, const int* in_sizes, int n_in,
                              void* d_out, int out_size, void* d_ws, size_t ws_size,
                              hipStream_t stream) {
    const float* x   = (const float*)d_in[0];
    const int*   ei  = (const int*)d_in[1];     // [2, E] row-major
    const float* W1  = (const float*)d_in[2];
    const float* b1  = (const float*)d_in[3];
    const float* W2  = (const float*)d_in[4];
    const float* b2  = (const float*)d_in[5];
    const float* W3  = (const float*)d_in[6];
    const float* b3  = (const float*)d_in[7];
    float* out = (float*)d_out;

    const int* src = ei;
    const int* dst = ei + N_EDGES;

    // ws layout (all 256B-aligned)
    char* ws = (char*)d_ws;
    int*   cnt     = (int*)ws;                             // 400 KB
    int*   off     = (int*)(ws + 0x80000);                 // 400 KB
    int*   cur     = (int*)(ws + 0x100000);                // 400 KB
    float* dinv    = (float*)(ws + 0x180000);              // 400 KB
    int*   csr_src = (int*)(ws + 0x200000);                // 4.8 MB
    float* bufA    = (float*)(ws + 0x700000);              // 25.6 MB
    float* bufB    = (float*)(ws + 0x700000 + 0x1A00000);  // 25.6 MB

    // ---- CSR build (once per launch) ----
    hipMemsetAsync(cnt, 0, N_NODES * sizeof(int), stream);
    k_count<<<(N_EDGES + 255) / 256, 256, 0, stream>>>(dst, cnt);
    k_scan<<<1, 1024, 0, stream>>>(cnt, off, cur);
    k_dinv<<<(N_NODES + 255) / 256, 256, 0, stream>>>(cnt, dinv);
    k_fill<<<(N_EDGES + 255) / 256, 256, 0, stream>>>(src, dst, cur, csr_src);

    const int gemm_blocks   = (N_NODES + 31) / 32;   // 3125
    const int gather_blocks = (N_NODES + 3) / 4;     // 25000 (4 waves/block)

    // Layer 1: x -> bufA (h), aggregate+relu -> bufB
    k_gemm<<<gemm_blocks, 256, 0, stream>>>(x, W1, bufA);
    k_gather<true><<<gather_blocks, 256, 0, stream>>>(bufA, dinv, off, cnt, csr_src, b1, bufB);

    // Layer 2: bufB -> bufA (h), aggregate+relu -> bufB
    k_gemm<<<gemm_blocks, 256, 0, stream>>>(bufB, W2, bufA);
    k_gather<true><<<gather_blocks, 256, 0, stream>>>(bufA, dinv, off, cnt, csr_src, b2, bufB);

    // Layer 3: bufB -> bufA (h), aggregate -> d_out
    k_gemm<<<gemm_blocks, 256, 0, stream>>>(bufB, W3, bufA);
    k_gather<false><<<gather_blocks, 256, 0, stream>>>(bufA, dinv, off, cnt, csr_src, b3, out);
}

// Round 3
// 731.644 us; speedup vs baseline: 4.6199x; 1.2353x over previous
//
#include <hip/hip_runtime.h>
#include <math.h>

#define N_NODES 100000
#define N_EDGES 1200000
#define DIM 64
#define SCAN_BLOCKS ((N_NODES + 1023) / 1024)   // 98

// ---------------- degree histogram ----------------

__global__ void k_count(const int* __restrict__ dst, int* __restrict__ cnt) {
    int e = blockIdx.x * blockDim.x + threadIdx.x;
    if (e < N_EDGES) atomicAdd(&cnt[dst[e]], 1);
}

// ---------------- 3-phase parallel exclusive scan ----------------
// Phase A: per-block local scan (1024 elems/block) + fused dinv compute.

__global__ void k_scanA(const int* __restrict__ cnt, int* __restrict__ off,
                        float* __restrict__ dinv, int* __restrict__ bsum) {
    __shared__ int buf[1024];
    int tid = threadIdx.x;
    int i = blockIdx.x * 1024 + tid;
    int v = (i < N_NODES) ? cnt[i] : 0;
    if (i < N_NODES) dinv[i] = rsqrtf((float)(v + 1));   // +1 self-loop
    buf[tid] = v;
    __syncthreads();
    for (int ofs = 1; ofs < 1024; ofs <<= 1) {           // Hillis-Steele inclusive
        int t = (tid >= ofs) ? buf[tid - ofs] : 0;
        __syncthreads();
        buf[tid] += t;
        __syncthreads();
    }
    if (i < N_NODES) off[i] = buf[tid] - v;              // local exclusive
    if (tid == 1023) bsum[blockIdx.x] = buf[1023];       // block total
}

// Phase B: single small block scans the 98 block sums (exclusive, in place).

__global__ void k_scanB(int* __restrict__ bsum) {
    __shared__ int buf[128];
    int tid = threadIdx.x;
    int v = (tid < SCAN_BLOCKS) ? bsum[tid] : 0;
    buf[tid] = v;
    __syncthreads();
    for (int ofs = 1; ofs < 128; ofs <<= 1) {
        int t = (tid >= ofs) ? buf[tid - ofs] : 0;
        __syncthreads();
        buf[tid] += t;
        __syncthreads();
    }
    if (tid < SCAN_BLOCKS) bsum[tid] = buf[tid] - v;
}

// Phase C: add block offsets; materialize off and cur.

__global__ void k_scanC(int* __restrict__ off, const int* __restrict__ bsum,
                        int* __restrict__ cur) {
    int i = blockIdx.x * blockDim.x + threadIdx.x;
    if (i < N_NODES) {
        int o = off[i] + bsum[i >> 10];
        off[i] = o;
        cur[i] = o;
    }
}

// ---------------- CSR bucket fill (one-time int atomics) ----------------

__global__ void k_fill(const int* __restrict__ src, const int* __restrict__ dst,
                       int* __restrict__ cur, int* __restrict__ csr_src) {
    int e = blockIdx.x * blockDim.x + threadIdx.x;
    if (e < N_EDGES) {
        int pos = atomicAdd(&cur[dst[e]], 1);
        csr_src[pos] = src[e];
    }
}

// ---------------- dense h = x @ W ----------------
// block = 256 (4 waves); each wave handles 8 nodes, lane = output column j.

__global__ void k_gemm(const float* __restrict__ x, const float* __restrict__ W,
                       float* __restrict__ h) {
    __shared__ float Wlds[DIM * DIM];
    int tid = threadIdx.x;
    for (int i = tid * 4; i < DIM * DIM; i += 256 * 4)
        *(float4*)&Wlds[i] = *(const float4*)&W[i];
    __syncthreads();

    int wave = tid >> 6;
    int lane = tid & 63;
    int n0 = (blockIdx.x * 4 + wave) * 8;
    if (n0 >= N_NODES) return;

    float acc[8];
#pragma unroll
    for (int m = 0; m < 8; ++m) acc[m] = 0.f;

    for (int k4 = 0; k4 < DIM / 4; ++k4) {
        float4 xv[8];
#pragma unroll
        for (int m = 0; m < 8; ++m)
            xv[m] = *(const float4*)&x[(size_t)(n0 + m) * DIM + k4 * 4];
#pragma unroll
        for (int kk = 0; kk < 4; ++kk) {
            float wk = Wlds[(k4 * 4 + kk) * DIM + lane];
#pragma unroll
            for (int m = 0; m < 8; ++m) {
                float xs = (kk == 0) ? xv[m].x : (kk == 1) ? xv[m].y
                         : (kk == 2) ? xv[m].z : xv[m].w;
                acc[m] = fmaf(xs, wk, acc[m]);
            }
        }
    }
#pragma unroll
    for (int m = 0; m < 8; ++m)
        h[(size_t)(n0 + m) * DIM + lane] = acc[m];
}

// ---------------- gather-side aggregation, fused self-loop + bias (+ relu) ----
// One wave per destination node; lane = output column. No atomics.

template <bool RELU_OUT>
__global__ void k_gather(const float* __restrict__ h, const float* __restrict__ dinv,
                         const int* __restrict__ off, const int* __restrict__ cnt,
                         const int* __restrict__ csr_src, const float* __restrict__ b,
                         float* __restrict__ out) {
    int node = blockIdx.x * (blockDim.x >> 6) + (threadIdx.x >> 6);
    int lane = threadIdx.x & 63;
    if (node >= N_NODES) return;

    float dd = dinv[node];
    float acc = fmaf(h[(size_t)node * DIM + lane], dd * dd, b[lane]);  // self-loop + bias

    int s0 = off[node];
    int n  = cnt[node];
    for (int i = 0; i < n; ++i) {
        int s = csr_src[s0 + i];                      // wave-uniform broadcast load
        float nrm = dinv[s] * dd;
        acc = fmaf(h[(size_t)s * DIM + lane], nrm, acc);  // coalesced 256B row gather
    }
    if (RELU_OUT) acc = fmaxf(acc, 0.f);
    out[(size_t)node * DIM + lane] = acc;
}

// ---------------- launch ----------------

extern "C" void kernel_launch(void* const* d_in, const int* in_sizes, int n_in,
                              void* d_out, int out_size, void* d_ws, size_t ws_size,
                              hipStream_t stream) {
    const float* x   = (const float*)d_in[0];
    const int*   ei  = (const int*)d_in[1];     // [2, E] row-major
    const float* W1  = (const float*)d_in[2];
    const float* b1  = (const float*)d_in[3];
    const float* W2  = (const float*)d_in[4];
    const float* b2  = (const float*)d_in[5];
    const float* W3  = (const float*)d_in[6];
    const float* b3  = (const float*)d_in[7];
    float* out = (float*)d_out;

    const int* src = ei;
    const int* dst = ei + N_EDGES;

    // ws layout (all 256B-aligned)
    char* ws = (char*)d_ws;
    int*   cnt     = (int*)ws;                             // 400 KB
    int*   off     = (int*)(ws + 0x80000);                 // 400 KB
    int*   cur     = (int*)(ws + 0x100000);                // 400 KB
    float* dinv    = (float*)(ws + 0x180000);              // 400 KB
    int*   bsum    = (int*)(ws + 0x1F0000);                // small
    int*   csr_src = (int*)(ws + 0x200000);                // 4.8 MB
    float* bufA    = (float*)(ws + 0x700000);              // 25.6 MB
    float* bufB    = (float*)(ws + 0x700000 + 0x1A00000);  // 25.6 MB

    // ---- CSR build (once per launch) ----
    hipMemsetAsync(cnt, 0, N_NODES * sizeof(int), stream);
    k_count<<<(N_EDGES + 255) / 256, 256, 0, stream>>>(dst, cnt);
    k_scanA<<<SCAN_BLOCKS, 1024, 0, stream>>>(cnt, off, dinv, bsum);
    k_scanB<<<1, 128, 0, stream>>>(bsum);
    k_scanC<<<(N_NODES + 255) / 256, 256, 0, stream>>>(off, bsum, cur);
    k_fill<<<(N_EDGES + 255) / 256, 256, 0, stream>>>(src, dst, cur, csr_src);

    const int gemm_blocks   = (N_NODES + 31) / 32;   // 3125
    const int gather_blocks = (N_NODES + 3) / 4;     // 25000 (4 waves/block)

    // Layer 1: x -> bufA (h), aggregate+relu -> bufB
    k_gemm<<<gemm_blocks, 256, 0, stream>>>(x, W1, bufA);
    k_gather<true><<<gather_blocks, 256, 0, stream>>>(bufA, dinv, off, cnt, csr_src, b1, bufB);

    // Layer 2: bufB -> bufA (h), aggregate+relu -> bufB
    k_gemm<<<gemm_blocks, 256, 0, stream>>>(bufB, W2, bufA);
    k_gather<true><<<gather_blocks, 256, 0, stream>>>(bufA, dinv, off, cnt, csr_src, b2, bufB);

    // Layer 3: bufB -> bufA (h), aggregate -> d_out
    k_gemm<<<gemm_blocks, 256, 0, stream>>>(bufB, W3, bufA);
    k_gather<false><<<gather_blocks, 256, 0, stream>>>(bufA, dinv, off, cnt, csr_src, b3, out);
}

// Round 4
// 526.601 us; speedup vs baseline: 6.4187x; 1.3894x over previous
//
#include <hip/hip_runtime.h>
#include <math.h>

#define N_NODES 100000
#define N_EDGES 1200000
#define DIM 64
#define SCAN_BLOCKS ((N_NODES + 1023) / 1024)   // 98
#define FUSED_BLOCKS 2048                        // 8 blocks/CU, 32 waves/CU

struct Edge { int s; float nrm; };               // 8B: src index + edge norm

// ---------------- degree histogram ----------------

__global__ void k_count(const int* __restrict__ dst, int* __restrict__ cnt) {
    int e = blockIdx.x * blockDim.x + threadIdx.x;
    if (e < N_EDGES) atomicAdd(&cnt[dst[e]], 1);
}

// ---------------- 3-phase parallel exclusive scan + dinv ----------------

__global__ void k_scanA(const int* __restrict__ cnt, int* __restrict__ off,
                        float* __restrict__ dinv, int* __restrict__ bsum) {
    __shared__ int buf[1024];
    int tid = threadIdx.x;
    int i = blockIdx.x * 1024 + tid;
    int v = (i < N_NODES) ? cnt[i] : 0;
    if (i < N_NODES) dinv[i] = rsqrtf((float)(v + 1));   // +1 self-loop
    buf[tid] = v;
    __syncthreads();
    for (int ofs = 1; ofs < 1024; ofs <<= 1) {           // Hillis-Steele inclusive
        int t = (tid >= ofs) ? buf[tid - ofs] : 0;
        __syncthreads();
        buf[tid] += t;
        __syncthreads();
    }
    if (i < N_NODES) off[i] = buf[tid] - v;              // local exclusive
    if (tid == 1023) bsum[blockIdx.x] = buf[1023];
}

__global__ void k_scanB(int* __restrict__ bsum) {
    __shared__ int buf[128];
    int tid = threadIdx.x;
    int v = (tid < SCAN_BLOCKS) ? bsum[tid] : 0;
    buf[tid] = v;
    __syncthreads();
    for (int ofs = 1; ofs < 128; ofs <<= 1) {
        int t = (tid >= ofs) ? buf[tid - ofs] : 0;
        __syncthreads();
        buf[tid] += t;
        __syncthreads();
    }
    if (tid < SCAN_BLOCKS) bsum[tid] = buf[tid] - v;
}

__global__ void k_scanC(int* __restrict__ off, const int* __restrict__ bsum,
                        int* __restrict__ cur) {
    int i = blockIdx.x * blockDim.x + threadIdx.x;
    if (i < N_NODES) {
        int o = off[i] + bsum[i >> 10];
        off[i] = o;
        cur[i] = o;
    }
}

// ---------------- CSR bucket fill: {src, dinv[src]*dinv[dst]} per edge -------

__global__ void k_fill(const int* __restrict__ src, const int* __restrict__ dst,
                       const float* __restrict__ dinv, int* __restrict__ cur,
                       Edge* __restrict__ csr) {
    int e = blockIdx.x * blockDim.x + threadIdx.x;
    if (e < N_EDGES) {
        int s = src[e], d = dst[e];
        int pos = atomicAdd(&cur[d], 1);
        Edge ed;
        ed.s = s;
        ed.nrm = dinv[s] * dinv[d];
        csr[pos] = ed;
    }
}

// ---------------- fused layer: out = relu?( A_hat @ in @ W + b ) -------------
// Uses (A_hat @ in) @ W == A_hat @ (in @ W). One wave per node (grid-stride).
// Aggregation: lane = (edge-group g in 0..3, column-quad q in 0..15); 4 edges
// in flight per wave, float4 row gathers. Cross-group shfl_xor reduction.
// Then dense 64x64 W-multiply from LDS with shfl broadcast of the aggregate.

template <bool RELU_OUT>
__global__ void k_fused(const float* __restrict__ in, const float* __restrict__ dinv,
                        const int* __restrict__ off, const int* __restrict__ cnt,
                        const Edge* __restrict__ csr, const float* __restrict__ W,
                        const float* __restrict__ b, float* __restrict__ out) {
    __shared__ float Wlds[DIM * DIM];
    int tid = threadIdx.x;
    for (int i = tid * 4; i < DIM * DIM; i += 256 * 4)
        *(float4*)&Wlds[i] = *(const float4*)&W[i];
    __syncthreads();

    const int lane = tid & 63;
    const int g = lane >> 4;        // edge group
    const int q = lane & 15;        // column quad (columns 4q..4q+3)
    const int gwave = blockIdx.x * 4 + (tid >> 6);
    const float bj = b[lane];

    for (int node = gwave; node < N_NODES; node += FUSED_BLOCKS * 4) {
        float dd = dinv[node];
        int s0 = off[node];
        int n = cnt[node];

        float ax = 0.f, ay = 0.f, az = 0.f, aw = 0.f;
        for (int i = g; i < n; i += 4) {
            Edge ed = csr[s0 + i];                       // 8B, seq per group
            float4 hv = *(const float4*)&in[(size_t)ed.s * DIM + q * 4];
            ax = fmaf(hv.x, ed.nrm, ax);
            ay = fmaf(hv.y, ed.nrm, ay);
            az = fmaf(hv.z, ed.nrm, az);
            aw = fmaf(hv.w, ed.nrm, aw);
        }
        // reduce across the 4 edge groups (lanes l, l^16, l^32, l^48)
        ax += __shfl_xor(ax, 16); ax += __shfl_xor(ax, 32);
        ay += __shfl_xor(ay, 16); ay += __shfl_xor(ay, 32);
        az += __shfl_xor(az, 16); az += __shfl_xor(az, 32);
        aw += __shfl_xor(aw, 16); aw += __shfl_xor(aw, 32);

        // self-loop: + dinv[node]^2 * in[node]
        float4 sv = *(const float4*)&in[(size_t)node * DIM + q * 4];
        float ss = dd * dd;
        ax = fmaf(sv.x, ss, ax);
        ay = fmaf(sv.y, ss, ay);
        az = fmaf(sv.z, ss, az);
        aw = fmaf(sv.w, ss, aw);
        // now lane k4 (0..15) holds agg[4*k4 .. 4*k4+3] (replicated in groups)

        // dense: o[j] = b[j] + sum_k agg[k] * W[k][j],  j = lane
        float o = bj;
#pragma unroll
        for (int k4 = 0; k4 < 16; ++k4) {
            float vx = __shfl(ax, k4);
            float vy = __shfl(ay, k4);
            float vz = __shfl(az, k4);
            float vw = __shfl(aw, k4);
            o = fmaf(vx, Wlds[(4 * k4 + 0) * DIM + lane], o);
            o = fmaf(vy, Wlds[(4 * k4 + 1) * DIM + lane], o);
            o = fmaf(vz, Wlds[(4 * k4 + 2) * DIM + lane], o);
            o = fmaf(vw, Wlds[(4 * k4 + 3) * DIM + lane], o);
        }
        if (RELU_OUT) o = fmaxf(o, 0.f);
        out[(size_t)node * DIM + lane] = o;
    }
}

// ---------------- launch ----------------

extern "C" void kernel_launch(void* const* d_in, const int* in_sizes, int n_in,
                              void* d_out, int out_size, void* d_ws, size_t ws_size,
                              hipStream_t stream) {
    const float* x   = (const float*)d_in[0];
    const int*   ei  = (const int*)d_in[1];     // [2, E] row-major
    const float* W1  = (const float*)d_in[2];
    const float* b1  = (const float*)d_in[3];
    const float* W2  = (const float*)d_in[4];
    const float* b2  = (const float*)d_in[5];
    const float* W3  = (const float*)d_in[6];
    const float* b3  = (const float*)d_in[7];
    float* out = (float*)d_out;

    const int* src = ei;
    const int* dst = ei + N_EDGES;

    // ws layout (256B-aligned)
    char* ws = (char*)d_ws;
    int*   cnt  = (int*)ws;                        // 400 KB
    int*   off  = (int*)(ws + 0x80000);            // 400 KB
    int*   cur  = (int*)(ws + 0x100000);           // 400 KB
    float* dinv = (float*)(ws + 0x180000);         // 400 KB
    int*   bsum = (int*)(ws + 0x1F0000);           // small
    Edge*  csr  = (Edge*)(ws + 0x200000);          // 9.6 MB
    float* bufA = (float*)(ws + 0xC00000);         // 25.6 MB
    float* bufB = (float*)(ws + 0xC00000 + 0x1A00000);  // 25.6 MB

    // ---- CSR build (once per launch) ----
    hipMemsetAsync(cnt, 0, N_NODES * sizeof(int), stream);
    k_count<<<(N_EDGES + 255) / 256, 256, 0, stream>>>(dst, cnt);
    k_scanA<<<SCAN_BLOCKS, 1024, 0, stream>>>(cnt, off, dinv, bsum);
    k_scanB<<<1, 128, 0, stream>>>(bsum);
    k_scanC<<<(N_NODES + 255) / 256, 256, 0, stream>>>(off, bsum, cur);
    k_fill<<<(N_EDGES + 255) / 256, 256, 0, stream>>>(src, dst, dinv, cur, csr);

    // ---- 3 fused layers ----
    k_fused<true><<<FUSED_BLOCKS, 256, 0, stream>>>(x, dinv, off, cnt, csr, W1, b1, bufA);
    k_fused<true><<<FUSED_BLOCKS, 256, 0, stream>>>(bufA, dinv, off, cnt, csr, W2, b2, bufB);
    k_fused<false><<<FUSED_BLOCKS, 256, 0, stream>>>(bufB, dinv, off, cnt, csr, W3, b3, out);
}